// Round 1
// baseline (4482.660 us; speedup 1.0000x reference)
//
#include <hip/hip_runtime.h>

#define NU 200000
#define NI 100000
#define NN 300000
#define NE 1500000
#define BD 384

// ---------------------------------------------------------------------------
// helpers
// ---------------------------------------------------------------------------
__device__ __forceinline__ void fma4(float4& a, float s, const float4& w) {
    a.x = fmaf(s, w.x, a.x);
    a.y = fmaf(s, w.y, a.y);
    a.z = fmaf(s, w.z, a.z);
    a.w = fmaf(s, w.w, a.w);
}

// ---------------------------------------------------------------------------
// user rows: e0 = user_emb + gender_emb[g] + age_emb[a]
// writes A (layer-0 features) and out = 0.25*e0
// grid covers NU*16 float4 lanes exactly (200000*16 / 256 = 12500 blocks)
// ---------------------------------------------------------------------------
__global__ __launch_bounds__(256) void user_init_k(
    const float4* __restrict__ user_emb,
    const float4* __restrict__ gender_emb,
    const float4* __restrict__ age_emb,
    const int* __restrict__ ug,
    const int* __restrict__ ua,
    float4* __restrict__ A,
    float4* __restrict__ out)
{
    int i = blockIdx.x * 256 + threadIdx.x;   // [0, NU*16)
    int u = i >> 4, q = i & 15;
    float4 e = user_emb[i];
    float4 g = gender_emb[ug[u] * 16 + q];
    float4 a = age_emb[ua[u] * 16 + q];
    e.x += g.x + a.x; e.y += g.y + a.y; e.z += g.z + a.z; e.w += g.w + a.w;
    A[i] = e;
    out[i] = make_float4(0.25f * e.x, 0.25f * e.y, 0.25f * e.z, 0.25f * e.w);
}

// ---------------------------------------------------------------------------
// item rows: e0 = item_emb + cat_emb[c] + bert @ W^T
// LDS-tiled fp32 GEMM: block = 256 threads handles 32 items, K chunked by 128.
//   Wc[k][d] transposed chunk, row pad 68 floats -> 16B-aligned b128 reads,
//   2-way bank aliasing only (free).
//   Bc[j][k] chunk, row pad 132 -> conflict-free stride-1 writes, b128 reads.
// Thread t: dims 4*(t&15)..+3, items (t>>4) and (t>>4)+16  -> acc 2x float4.
// 100000/32 = 3125 blocks exactly.
// ---------------------------------------------------------------------------
__global__ __launch_bounds__(256) void item_init_k(
    const float* __restrict__ bert,        // [NI][384]
    const float* __restrict__ W,           // [64][384]
    const float4* __restrict__ item_emb,   // [NI*16]
    const float4* __restrict__ cat_emb,    // [11*16]
    const int* __restrict__ icat,
    float4* __restrict__ A,                // node buffer, float4 view [NN*16]
    float4* __restrict__ out)
{
    __shared__ float Wc[128][68];
    __shared__ float Bc[32][132];

    const int t  = threadIdx.x;
    const int i0 = blockIdx.x * 32;
    const int dg = t & 15;     // dim quad: dims 4*dg .. 4*dg+3
    const int ig = t >> 4;     // item group: items ig, ig+16

    float4 acc_a = make_float4(0.f, 0.f, 0.f, 0.f);
    float4 acc_b = make_float4(0.f, 0.f, 0.f, 0.f);

    for (int kc = 0; kc < 3; ++kc) {
        const int k0 = kc * 128;
        __syncthreads();   // protect previous chunk's reads before overwrite
        // stage W chunk (64 dims x 128 k), transposed into Wc[k][d]
        #pragma unroll
        for (int m = 0; m < 32; ++m) {
            int idx = m * 256 + t;             // 8192 elements
            int d = idx >> 7, k = idx & 127;
            Wc[k][d] = W[d * BD + k0 + k];     // global read coalesced over k
        }
        // stage bert chunk (32 items x 128 k)
        #pragma unroll
        for (int m = 0; m < 16; ++m) {
            int idx = m * 256 + t;             // 4096 elements
            int j = idx >> 7, k = idx & 127;
            Bc[j][k] = bert[(size_t)(i0 + j) * BD + k0 + k];
        }
        __syncthreads();

        #pragma unroll 4
        for (int k = 0; k < 128; k += 4) {
            float4 w0 = *(const float4*)&Wc[k + 0][dg * 4];
            float4 w1 = *(const float4*)&Wc[k + 1][dg * 4];
            float4 w2 = *(const float4*)&Wc[k + 2][dg * 4];
            float4 w3 = *(const float4*)&Wc[k + 3][dg * 4];
            float4 ba = *(const float4*)&Bc[ig][k];
            float4 bb = *(const float4*)&Bc[ig + 16][k];
            fma4(acc_a, ba.x, w0); fma4(acc_a, ba.y, w1);
            fma4(acc_a, ba.z, w2); fma4(acc_a, ba.w, w3);
            fma4(acc_b, bb.x, w0); fma4(acc_b, bb.y, w1);
            fma4(acc_b, bb.z, w2); fma4(acc_b, bb.w, w3);
        }
    }

    // epilogue: add item_emb + cat_emb, write A and out
    #pragma unroll
    for (int jj = 0; jj < 2; ++jj) {
        const float4 acc = jj ? acc_b : acc_a;
        const int gi = i0 + ig + jj * 16;          // item index
        const int vidx = gi * 16 + dg;             // float4 index in item arrays
        float4 base = item_emb[vidx];
        float4 ce   = cat_emb[icat[gi] * 16 + dg];
        float4 e;
        e.x = base.x + ce.x + acc.x;
        e.y = base.y + ce.y + acc.y;
        e.z = base.z + ce.z + acc.z;
        e.w = base.w + ce.w + acc.w;
        const int nidx = (NU + gi) * 16 + dg;      // node-major float4 index
        A[nidx] = e;
        out[nidx] = make_float4(0.25f * e.x, 0.25f * e.y, 0.25f * e.z, 0.25f * e.w);
    }
}

// ---------------------------------------------------------------------------
// COO SpMM scatter: y[row] += val * x[col]
// thread t: edge e = t>>4, dim quad q = t&15; 4 fp32 HW atomics per thread.
// NE*16 / 256 = 93750 blocks exactly.
// ---------------------------------------------------------------------------
__global__ __launch_bounds__(256) void spmm_k(
    const float4* __restrict__ x,   // [NN*16]
    float* __restrict__ y,          // [NN*64], pre-zeroed
    const float* __restrict__ val,
    const int* __restrict__ row,
    const int* __restrict__ col)
{
    int t = blockIdx.x * 256 + threadIdx.x;   // [0, NE*16)
    int e = t >> 4, q = t & 15;
    float v = val[e];
    int r = row[e], c = col[e];
    float4 xv = x[c * 16 + q];
    float* yp = y + (size_t)r * 64 + q * 4;
    unsafeAtomicAdd(yp + 0, v * xv.x);
    unsafeAtomicAdd(yp + 1, v * xv.y);
    unsafeAtomicAdd(yp + 2, v * xv.z);
    unsafeAtomicAdd(yp + 3, v * xv.w);
}

// ---------------------------------------------------------------------------
// out += 0.25*x, optionally zero z (the next layer's target buffer)
// NN*16 / 256 = 18750 blocks exactly.
// ---------------------------------------------------------------------------
__global__ __launch_bounds__(256) void acc_zero_k(
    float4* __restrict__ out,
    const float4* __restrict__ x,
    float4* __restrict__ z,
    int do_zero)
{
    int i = blockIdx.x * 256 + threadIdx.x;   // [0, NN*16)
    float4 o = out[i];
    float4 xv = x[i];
    o.x = fmaf(0.25f, xv.x, o.x);
    o.y = fmaf(0.25f, xv.y, o.y);
    o.z = fmaf(0.25f, xv.z, o.z);
    o.w = fmaf(0.25f, xv.w, o.w);
    out[i] = o;
    if (do_zero) z[i] = make_float4(0.f, 0.f, 0.f, 0.f);
}

// ---------------------------------------------------------------------------
extern "C" void kernel_launch(void* const* d_in, const int* in_sizes, int n_in,
                              void* d_out, int out_size, void* d_ws, size_t ws_size,
                              hipStream_t stream)
{
    const float* user_emb   = (const float*)d_in[0];
    const float* item_emb   = (const float*)d_in[1];
    const float* gender_emb = (const float*)d_in[2];
    const float* age_emb    = (const float*)d_in[3];
    const float* cat_emb    = (const float*)d_in[4];
    const float* bert_w     = (const float*)d_in[5];
    const float* item_bert  = (const float*)d_in[6];
    const float* adj_val    = (const float*)d_in[7];
    const int*   user_gender= (const int*)d_in[8];
    const int*   user_age   = (const int*)d_in[9];
    const int*   item_cat   = (const int*)d_in[10];
    const int*   adj_row    = (const int*)d_in[11];
    const int*   adj_col    = (const int*)d_in[12];

    float* out = (float*)d_out;
    float* A = (float*)d_ws;                       // [NN*64] layer features (ping)
    float* B = A + (size_t)NN * 64;                // [NN*64] layer features (pong)
    const size_t node_bytes = (size_t)NN * 64 * sizeof(float);

    // B will receive layer-1 output via atomics -> zero it
    hipMemsetAsync(B, 0, node_bytes, stream);

    // layer-0 features into A; out = 0.25 * e0
    user_init_k<<<12500, 256, 0, stream>>>(
        (const float4*)user_emb, (const float4*)gender_emb, (const float4*)age_emb,
        user_gender, user_age, (float4*)A, (float4*)out);
    item_init_k<<<3125, 256, 0, stream>>>(
        item_bert, bert_w, (const float4*)item_emb, (const float4*)cat_emb,
        item_cat, (float4*)A, (float4*)out);

    // layer 1: B += f(A); out += 0.25*B; zero A for layer 2
    spmm_k<<<93750, 256, 0, stream>>>((const float4*)A, B, adj_val, adj_row, adj_col);
    acc_zero_k<<<18750, 256, 0, stream>>>((float4*)out, (const float4*)B, (float4*)A, 1);

    // layer 2: A += f(B); out += 0.25*A; zero B for layer 3
    spmm_k<<<93750, 256, 0, stream>>>((const float4*)B, A, adj_val, adj_row, adj_col);
    acc_zero_k<<<18750, 256, 0, stream>>>((float4*)out, (const float4*)A, (float4*)B, 1);

    // layer 3: B += f(A); out += 0.25*B
    spmm_k<<<93750, 256, 0, stream>>>((const float4*)A, B, adj_val, adj_row, adj_col);
    acc_zero_k<<<18750, 256, 0, stream>>>((float4*)out, (const float4*)B, (float4*)B, 0);
}

// Round 2
// 1019.503 us; speedup vs baseline: 4.3969x; 4.3969x over previous
//
#include <hip/hip_runtime.h>

#define NU 200000
#define NI 100000
#define NN 300000
#define NE 1500000
#define BD 384

#define SCAN1_BLOCKS 293   // ceil(NN / 1024)

// ---------------------------------------------------------------------------
__device__ __forceinline__ void fma4(float4& a, float s, const float4& w) {
    a.x = fmaf(s, w.x, a.x);
    a.y = fmaf(s, w.y, a.y);
    a.z = fmaf(s, w.z, a.z);
    a.w = fmaf(s, w.w, a.w);
}

// ---------------------------------------------------------------------------
// user rows: e0 = user_emb + gender_emb[g] + age_emb[a]
// writes A (layer-0 features) and out = 0.25*e0
// 200000*16 / 256 = 12500 blocks exactly
// ---------------------------------------------------------------------------
__global__ __launch_bounds__(256) void user_init_k(
    const float4* __restrict__ user_emb,
    const float4* __restrict__ gender_emb,
    const float4* __restrict__ age_emb,
    const int* __restrict__ ug,
    const int* __restrict__ ua,
    float4* __restrict__ A,
    float4* __restrict__ out)
{
    int i = blockIdx.x * 256 + threadIdx.x;   // [0, NU*16)
    int u = i >> 4, q = i & 15;
    float4 e = user_emb[i];
    float4 g = gender_emb[ug[u] * 16 + q];
    float4 a = age_emb[ua[u] * 16 + q];
    e.x += g.x + a.x; e.y += g.y + a.y; e.z += g.z + a.z; e.w += g.w + a.w;
    A[i] = e;
    out[i] = make_float4(0.25f * e.x, 0.25f * e.y, 0.25f * e.z, 0.25f * e.w);
}

// ---------------------------------------------------------------------------
// item rows: e0 = item_emb + cat_emb[c] + bert @ W^T   (LDS-tiled fp32 GEMM)
// 100000/32 = 3125 blocks exactly.
// ---------------------------------------------------------------------------
__global__ __launch_bounds__(256) void item_init_k(
    const float* __restrict__ bert,        // [NI][384]
    const float* __restrict__ W,           // [64][384]
    const float4* __restrict__ item_emb,   // [NI*16]
    const float4* __restrict__ cat_emb,    // [11*16]
    const int* __restrict__ icat,
    float4* __restrict__ A,                // node buffer, float4 view [NN*16]
    float4* __restrict__ out)
{
    __shared__ float Wc[128][68];
    __shared__ float Bc[32][132];

    const int t  = threadIdx.x;
    const int i0 = blockIdx.x * 32;
    const int dg = t & 15;     // dim quad: dims 4*dg .. 4*dg+3
    const int ig = t >> 4;     // item group: items ig, ig+16

    float4 acc_a = make_float4(0.f, 0.f, 0.f, 0.f);
    float4 acc_b = make_float4(0.f, 0.f, 0.f, 0.f);

    for (int kc = 0; kc < 3; ++kc) {
        const int k0 = kc * 128;
        __syncthreads();
        #pragma unroll
        for (int m = 0; m < 32; ++m) {
            int idx = m * 256 + t;             // 8192 elements
            int d = idx >> 7, k = idx & 127;
            Wc[k][d] = W[d * BD + k0 + k];
        }
        #pragma unroll
        for (int m = 0; m < 16; ++m) {
            int idx = m * 256 + t;             // 4096 elements
            int j = idx >> 7, k = idx & 127;
            Bc[j][k] = bert[(size_t)(i0 + j) * BD + k0 + k];
        }
        __syncthreads();

        #pragma unroll 4
        for (int k = 0; k < 128; k += 4) {
            float4 w0 = *(const float4*)&Wc[k + 0][dg * 4];
            float4 w1 = *(const float4*)&Wc[k + 1][dg * 4];
            float4 w2 = *(const float4*)&Wc[k + 2][dg * 4];
            float4 w3 = *(const float4*)&Wc[k + 3][dg * 4];
            float4 ba = *(const float4*)&Bc[ig][k];
            float4 bb = *(const float4*)&Bc[ig + 16][k];
            fma4(acc_a, ba.x, w0); fma4(acc_a, ba.y, w1);
            fma4(acc_a, ba.z, w2); fma4(acc_a, ba.w, w3);
            fma4(acc_b, bb.x, w0); fma4(acc_b, bb.y, w1);
            fma4(acc_b, bb.z, w2); fma4(acc_b, bb.w, w3);
        }
    }

    #pragma unroll
    for (int jj = 0; jj < 2; ++jj) {
        const float4 acc = jj ? acc_b : acc_a;
        const int gi = i0 + ig + jj * 16;
        const int vidx = gi * 16 + dg;
        float4 base = item_emb[vidx];
        float4 ce   = cat_emb[icat[gi] * 16 + dg];
        float4 e;
        e.x = base.x + ce.x + acc.x;
        e.y = base.y + ce.y + acc.y;
        e.z = base.z + ce.z + acc.z;
        e.w = base.w + ce.w + acc.w;
        const int nidx = (NU + gi) * 16 + dg;
        A[nidx] = e;
        out[nidx] = make_float4(0.25f * e.x, 0.25f * e.y, 0.25f * e.z, 0.25f * e.w);
    }
}

// ---------------------------------------------------------------------------
// CSR build: histogram -> 2-level exclusive scan -> scatter {col,val} pairs
// ---------------------------------------------------------------------------
__global__ __launch_bounds__(256) void hist_k(
    const int* __restrict__ row, int* __restrict__ counts)
{
    int e = blockIdx.x * 256 + threadIdx.x;
    if (e < NE) atomicAdd(&counts[row[e]], 1);
}

// block scans 1024 elements (4/thread); in-place safe (reads before writes)
__global__ __launch_bounds__(256) void scan1_k(
    const int* __restrict__ counts, int* __restrict__ offs,
    int* __restrict__ blksum)
{
    __shared__ int s[256];
    int t = threadIdx.x;
    int base = blockIdx.x * 1024 + t * 4;
    int c0 = 0, c1 = 0, c2 = 0, c3 = 0;
    if (base + 3 < NN) {
        int4 c = *(const int4*)&counts[base];
        c0 = c.x; c1 = c.y; c2 = c.z; c3 = c.w;
    } else {
        if (base + 0 < NN) c0 = counts[base + 0];
        if (base + 1 < NN) c1 = counts[base + 1];
        if (base + 2 < NN) c2 = counts[base + 2];
    }
    int tsum = c0 + c1 + c2 + c3;
    s[t] = tsum;
    __syncthreads();
    for (int d = 1; d < 256; d <<= 1) {
        int v = (t >= d) ? s[t - d] : 0;
        __syncthreads();
        s[t] += v;
        __syncthreads();
    }
    if (t == 255) blksum[blockIdx.x] = s[255];
    int e0 = s[t] - tsum, e1 = e0 + c0, e2 = e1 + c1, e3 = e2 + c2;
    if (base + 0 < NN) offs[base + 0] = e0;
    if (base + 1 < NN) offs[base + 1] = e1;
    if (base + 2 < NN) offs[base + 2] = e2;
    if (base + 3 < NN) offs[base + 3] = e3;
}

// exclusive scan of the SCAN1_BLOCKS block sums, in place (1 block, 512 thr)
__global__ __launch_bounds__(512) void scan2_k(int* __restrict__ blksum)
{
    __shared__ int s[512];
    int t = threadIdx.x;
    int v = (t < SCAN1_BLOCKS) ? blksum[t] : 0;
    s[t] = v;
    __syncthreads();
    for (int d = 1; d < 512; d <<= 1) {
        int x = (t >= d) ? s[t - d] : 0;
        __syncthreads();
        s[t] += x;
        __syncthreads();
    }
    if (t < SCAN1_BLOCKS) blksum[t] = s[t] - v;
}

__global__ __launch_bounds__(256) void addoff_k(
    int* __restrict__ offs, const int* __restrict__ blkoff,
    int* __restrict__ cursor)
{
    int i = blockIdx.x * 256 + threadIdx.x;
    if (i < NN) {
        int o = offs[i] + blkoff[i >> 10];
        offs[i] = o;
        cursor[i] = o;
    }
}

// scatter edges to CSR order; after this, cursor[r] == row-end offset
__global__ __launch_bounds__(256) void scatter_k(
    const int* __restrict__ row, const int* __restrict__ col,
    const float* __restrict__ val,
    int* __restrict__ cursor, int2* __restrict__ edges)
{
    int e = blockIdx.x * 256 + threadIdx.x;
    if (e < NE) {
        int r = row[e];
        int pos = atomicAdd(&cursor[r], 1);
        edges[pos] = make_int2(col[e], __float_as_int(val[e]));
    }
}

// ---------------------------------------------------------------------------
// CSR gather SpMM + fused accumulation: y[r] = sum val*x[col]; out += 0.25*y
// 16 lanes per row (float4 each), 16 rows/block. NN/16 = 18750 blocks exactly.
// ---------------------------------------------------------------------------
__global__ __launch_bounds__(256) void spmm_csr_k(
    const float4* __restrict__ x,
    float4* __restrict__ y,
    float4* __restrict__ out,
    const int* __restrict__ offs,
    const int* __restrict__ ends,
    const int2* __restrict__ edges,
    int store_y)
{
    int t = threadIdx.x;
    int r = blockIdx.x * 16 + (t >> 4);
    int q = t & 15;
    int s = offs[r], e = ends[r];
    float4 acc = make_float4(0.f, 0.f, 0.f, 0.f);
    for (int k = s; k < e; ++k) {
        int2 cv = edges[k];
        float v = __int_as_float(cv.y);
        float4 xv = x[cv.x * 16 + q];
        fma4(acc, v, xv);
    }
    int oi = r * 16 + q;
    if (store_y) y[oi] = acc;
    float4 o = out[oi];
    o.x = fmaf(0.25f, acc.x, o.x);
    o.y = fmaf(0.25f, acc.y, o.y);
    o.z = fmaf(0.25f, acc.z, o.z);
    o.w = fmaf(0.25f, acc.w, o.w);
    out[oi] = o;
}

// ---------------------------------------------------------------------------
extern "C" void kernel_launch(void* const* d_in, const int* in_sizes, int n_in,
                              void* d_out, int out_size, void* d_ws, size_t ws_size,
                              hipStream_t stream)
{
    const float* user_emb    = (const float*)d_in[0];
    const float* item_emb    = (const float*)d_in[1];
    const float* gender_emb  = (const float*)d_in[2];
    const float* age_emb     = (const float*)d_in[3];
    const float* cat_emb     = (const float*)d_in[4];
    const float* bert_w      = (const float*)d_in[5];
    const float* item_bert   = (const float*)d_in[6];
    const float* adj_val     = (const float*)d_in[7];
    const int*   user_gender = (const int*)d_in[8];
    const int*   user_age    = (const int*)d_in[9];
    const int*   item_cat    = (const int*)d_in[10];
    const int*   adj_row     = (const int*)d_in[11];
    const int*   adj_col     = (const int*)d_in[12];

    float* out = (float*)d_out;

    // workspace layout (all 16B aligned)
    float* A      = (float*)d_ws;                 // [NN*64]
    float* B      = A + (size_t)NN * 64;          // [NN*64]
    int2*  edges  = (int2*)(B + (size_t)NN * 64); // [NE]
    int*   offs   = (int*)(edges + NE);           // [NN] (also counts)
    int*   cursor = offs + NN;                    // [NN]
    int*   blksum = cursor + NN;                  // [512]

    // --- CSR build ---
    hipMemsetAsync(offs, 0, (size_t)NN * sizeof(int), stream);
    hist_k<<<5860, 256, 0, stream>>>(adj_row, offs);
    scan1_k<<<SCAN1_BLOCKS, 256, 0, stream>>>(offs, offs, blksum);
    scan2_k<<<1, 512, 0, stream>>>(blksum);
    addoff_k<<<1172, 256, 0, stream>>>(offs, blksum, cursor);
    scatter_k<<<5860, 256, 0, stream>>>(adj_row, adj_col, adj_val, cursor, edges);

    // --- layer-0 features into A; out = 0.25*e0 ---
    user_init_k<<<12500, 256, 0, stream>>>(
        (const float4*)user_emb, (const float4*)gender_emb, (const float4*)age_emb,
        user_gender, user_age, (float4*)A, (float4*)out);
    item_init_k<<<3125, 256, 0, stream>>>(
        item_bert, bert_w, (const float4*)item_emb, (const float4*)cat_emb,
        item_cat, (float4*)A, (float4*)out);

    // --- 3 propagation layers, out-accumulation fused ---
    spmm_csr_k<<<18750, 256, 0, stream>>>(
        (const float4*)A, (float4*)B, (float4*)out, offs, cursor, edges, 1);
    spmm_csr_k<<<18750, 256, 0, stream>>>(
        (const float4*)B, (float4*)A, (float4*)out, offs, cursor, edges, 1);
    spmm_csr_k<<<18750, 256, 0, stream>>>(
        (const float4*)A, (float4*)B, (float4*)out, offs, cursor, edges, 0);
}

// Round 3
// 778.177 us; speedup vs baseline: 5.7605x; 1.3101x over previous
//
#include <hip/hip_runtime.h>
#include <hip/hip_bf16.h>

#define NU 200000
#define NI 100000
#define NN 300000
#define NE 1500000
#define BD 384

#define SCAN1_BLOCKS 293   // ceil(NN / 1024)

typedef __attribute__((ext_vector_type(8))) short short8;
typedef __attribute__((ext_vector_type(4))) float floatx4;

// ---------------------------------------------------------------------------
__device__ __forceinline__ void fma4(float4& a, float s, const float4& w) {
    a.x = fmaf(s, w.x, a.x);
    a.y = fmaf(s, w.y, a.y);
    a.z = fmaf(s, w.z, a.z);
    a.w = fmaf(s, w.w, a.w);
}

// pack 8 fp32 -> 8 bf16 (RNE)
__device__ __forceinline__ short8 cvt8(const float4 a, const float4 b) {
    union { short8 v; __hip_bfloat16 e[8]; } u;
    u.e[0] = __float2bfloat16(a.x); u.e[1] = __float2bfloat16(a.y);
    u.e[2] = __float2bfloat16(a.z); u.e[3] = __float2bfloat16(a.w);
    u.e[4] = __float2bfloat16(b.x); u.e[5] = __float2bfloat16(b.y);
    u.e[6] = __float2bfloat16(b.z); u.e[7] = __float2bfloat16(b.w);
    return u.v;
}

// ---------------------------------------------------------------------------
// user rows: A[u] = user_emb + gender_emb[g] + age_emb[a]   (out deferred)
// 200000*16 / 256 = 12500 blocks exactly
// ---------------------------------------------------------------------------
__global__ __launch_bounds__(256) void user_init_k(
    const float4* __restrict__ user_emb,
    const float4* __restrict__ gender_emb,
    const float4* __restrict__ age_emb,
    const int* __restrict__ ug,
    const int* __restrict__ ua,
    float4* __restrict__ A)
{
    int i = blockIdx.x * 256 + threadIdx.x;   // [0, NU*16)
    int u = i >> 4, q = i & 15;
    float4 e = user_emb[i];
    float4 g = gender_emb[ug[u] * 16 + q];
    float4 a = age_emb[ua[u] * 16 + q];
    e.x += g.x + a.x; e.y += g.y + a.y; e.z += g.z + a.z; e.w += g.w + a.w;
    A[i] = e;
}

// ---------------------------------------------------------------------------
// item rows via bf16 MFMA, no LDS:
//   A[NU+i] = item_emb[i] + cat_emb[icat[i]] + bert[i] @ W^T
// One wave = 16 items x 64 dims = 4 C-tiles; K-loop 384 in steps of 32.
// A-frag:  bert[(i0+m16)][k0 + q*8 + j]      (free dim = lane&15, k = quad*8+j)
// B-frag:  W[n0 + m16][k0 + q*8 + j]         (B[k][n] = W[n][k], n = lane&15)
// C/D:     item = q*4 + reg, dim = n0 + m16  (col=lane&15, row=quad*4+reg)
// grid: ceil(6250 waves / 4) = 1563 blocks
// ---------------------------------------------------------------------------
__global__ __launch_bounds__(256) void item_init_k(
    const float* __restrict__ bert,        // [NI][384]
    const float* __restrict__ W,           // [64][384]
    const float* __restrict__ item_emb,    // [NI][64]
    const float* __restrict__ cat_emb,     // [11][64]
    const int* __restrict__ icat,
    float* __restrict__ A)                 // [NN][64]
{
    const int lid = threadIdx.x & 63;
    const int wv  = threadIdx.x >> 6;
    const int i0  = (blockIdx.x * 4 + wv) * 16;
    if (i0 >= NI) return;
    const int m16 = lid & 15;
    const int q   = lid >> 4;

    const float* ab = bert + (size_t)(i0 + m16) * BD + q * 8;
    const float* b0 = W + (size_t)(m16 +  0) * BD + q * 8;
    const float* b1 = W + (size_t)(m16 + 16) * BD + q * 8;
    const float* b2 = W + (size_t)(m16 + 32) * BD + q * 8;
    const float* b3 = W + (size_t)(m16 + 48) * BD + q * 8;

    floatx4 cf[4];
    cf[0] = (floatx4){0.f, 0.f, 0.f, 0.f};
    cf[1] = cf[0]; cf[2] = cf[0]; cf[3] = cf[0];

    for (int k0 = 0; k0 < BD; k0 += 32) {
        short8 af = cvt8(*(const float4*)(ab + k0), *(const float4*)(ab + k0 + 4));
        short8 f0 = cvt8(*(const float4*)(b0 + k0), *(const float4*)(b0 + k0 + 4));
        short8 f1 = cvt8(*(const float4*)(b1 + k0), *(const float4*)(b1 + k0 + 4));
        short8 f2 = cvt8(*(const float4*)(b2 + k0), *(const float4*)(b2 + k0 + 4));
        short8 f3 = cvt8(*(const float4*)(b3 + k0), *(const float4*)(b3 + k0 + 4));
        cf[0] = __builtin_amdgcn_mfma_f32_16x16x32_bf16(af, f0, cf[0], 0, 0, 0);
        cf[1] = __builtin_amdgcn_mfma_f32_16x16x32_bf16(af, f1, cf[1], 0, 0, 0);
        cf[2] = __builtin_amdgcn_mfma_f32_16x16x32_bf16(af, f2, cf[2], 0, 0, 0);
        cf[3] = __builtin_amdgcn_mfma_f32_16x16x32_bf16(af, f3, cf[3], 0, 0, 0);
    }

    #pragma unroll
    for (int r = 0; r < 4; ++r) {
        const int item = i0 + q * 4 + r;
        const int cat  = icat[item];
        const size_t eb = (size_t)item * 64;
        const size_t abn = (size_t)(NU + item) * 64;
        #pragma unroll
        for (int td = 0; td < 4; ++td) {
            const int d = td * 16 + m16;
            A[abn + d] = cf[td][r] + item_emb[eb + d] + cat_emb[cat * 64 + d];
        }
    }
}

// ---------------------------------------------------------------------------
// CSR build: histogram -> 2-level exclusive scan -> scatter {col,val} pairs
// ---------------------------------------------------------------------------
__global__ __launch_bounds__(256) void hist_k(
    const int* __restrict__ row, int* __restrict__ counts)
{
    int e = blockIdx.x * 256 + threadIdx.x;
    if (e < NE) atomicAdd(&counts[row[e]], 1);
}

__global__ __launch_bounds__(256) void scan1_k(
    const int* __restrict__ counts, int* __restrict__ offs,
    int* __restrict__ blksum)
{
    __shared__ int s[256];
    int t = threadIdx.x;
    int base = blockIdx.x * 1024 + t * 4;
    int c0 = 0, c1 = 0, c2 = 0, c3 = 0;
    if (base + 3 < NN) {
        int4 c = *(const int4*)&counts[base];
        c0 = c.x; c1 = c.y; c2 = c.z; c3 = c.w;
    } else {
        if (base + 0 < NN) c0 = counts[base + 0];
        if (base + 1 < NN) c1 = counts[base + 1];
        if (base + 2 < NN) c2 = counts[base + 2];
    }
    int tsum = c0 + c1 + c2 + c3;
    s[t] = tsum;
    __syncthreads();
    for (int d = 1; d < 256; d <<= 1) {
        int v = (t >= d) ? s[t - d] : 0;
        __syncthreads();
        s[t] += v;
        __syncthreads();
    }
    if (t == 255) blksum[blockIdx.x] = s[255];
    int e0 = s[t] - tsum, e1 = e0 + c0, e2 = e1 + c1, e3 = e2 + c2;
    if (base + 0 < NN) offs[base + 0] = e0;
    if (base + 1 < NN) offs[base + 1] = e1;
    if (base + 2 < NN) offs[base + 2] = e2;
    if (base + 3 < NN) offs[base + 3] = e3;
}

__global__ __launch_bounds__(512) void scan2_k(int* __restrict__ blksum)
{
    __shared__ int s[512];
    int t = threadIdx.x;
    int v = (t < SCAN1_BLOCKS) ? blksum[t] : 0;
    s[t] = v;
    __syncthreads();
    for (int d = 1; d < 512; d <<= 1) {
        int x = (t >= d) ? s[t - d] : 0;
        __syncthreads();
        s[t] += x;
        __syncthreads();
    }
    if (t < SCAN1_BLOCKS) blksum[t] = s[t] - v;
}

__global__ __launch_bounds__(256) void addoff_k(
    int* __restrict__ offs, const int* __restrict__ blkoff,
    int* __restrict__ cursor)
{
    int i = blockIdx.x * 256 + threadIdx.x;
    if (i < NN) {
        int o = offs[i] + blkoff[i >> 10];
        offs[i] = o;
        cursor[i] = o;
    }
}

__global__ __launch_bounds__(256) void scatter_k(
    const int* __restrict__ row, const int* __restrict__ col,
    const float* __restrict__ val,
    int* __restrict__ cursor, int2* __restrict__ edges)
{
    int e = blockIdx.x * 256 + threadIdx.x;
    if (e < NE) {
        int r = row[e];
        int pos = atomicAdd(&cursor[r], 1);
        edges[pos] = make_int2(col[e], __float_as_int(val[e]));
    }
}

// ---------------------------------------------------------------------------
// CSR gather SpMM, 4-way unrolled for memory-level parallelism.
// mode 1: y[r]=acc; out[r] = 0.25*(x[r]+acc)   (pure write — layer 1)
// mode 2: y[r]=acc; out[r] += 0.25*acc
// mode 3: out[r] += 0.25*acc                    (no y store — last layer)
// 16 lanes per row (float4 each), 16 rows/block. NN/16 = 18750 blocks.
// ---------------------------------------------------------------------------
__global__ __launch_bounds__(256) void spmm_csr_k(
    const float4* __restrict__ x,
    float4* __restrict__ y,
    float4* __restrict__ out,
    const int* __restrict__ offs,
    const int* __restrict__ ends,
    const int2* __restrict__ edges,
    int mode)
{
    int t = threadIdx.x;
    int r = blockIdx.x * 16 + (t >> 4);
    int q = t & 15;
    int s = offs[r], e = ends[r];
    float4 acc = make_float4(0.f, 0.f, 0.f, 0.f);
    int k = s;
    for (; k + 4 <= e; k += 4) {
        int2 c0 = edges[k + 0];
        int2 c1 = edges[k + 1];
        int2 c2 = edges[k + 2];
        int2 c3 = edges[k + 3];
        float4 x0 = x[c0.x * 16 + q];
        float4 x1 = x[c1.x * 16 + q];
        float4 x2 = x[c2.x * 16 + q];
        float4 x3 = x[c3.x * 16 + q];
        fma4(acc, __int_as_float(c0.y), x0);
        fma4(acc, __int_as_float(c1.y), x1);
        fma4(acc, __int_as_float(c2.y), x2);
        fma4(acc, __int_as_float(c3.y), x3);
    }
    for (; k < e; ++k) {
        int2 cv = edges[k];
        fma4(acc, __int_as_float(cv.y), x[cv.x * 16 + q]);
    }
    int oi = r * 16 + q;
    if (mode != 3) y[oi] = acc;
    float4 o;
    if (mode == 1) {
        float4 xr = x[oi];
        o = make_float4(0.25f * (xr.x + acc.x), 0.25f * (xr.y + acc.y),
                        0.25f * (xr.z + acc.z), 0.25f * (xr.w + acc.w));
    } else {
        o = out[oi];
        o.x = fmaf(0.25f, acc.x, o.x);
        o.y = fmaf(0.25f, acc.y, o.y);
        o.z = fmaf(0.25f, acc.z, o.z);
        o.w = fmaf(0.25f, acc.w, o.w);
    }
    out[oi] = o;
}

// ---------------------------------------------------------------------------
extern "C" void kernel_launch(void* const* d_in, const int* in_sizes, int n_in,
                              void* d_out, int out_size, void* d_ws, size_t ws_size,
                              hipStream_t stream)
{
    const float* user_emb    = (const float*)d_in[0];
    const float* item_emb    = (const float*)d_in[1];
    const float* gender_emb  = (const float*)d_in[2];
    const float* age_emb     = (const float*)d_in[3];
    const float* cat_emb     = (const float*)d_in[4];
    const float* bert_w      = (const float*)d_in[5];
    const float* item_bert   = (const float*)d_in[6];
    const float* adj_val     = (const float*)d_in[7];
    const int*   user_gender = (const int*)d_in[8];
    const int*   user_age    = (const int*)d_in[9];
    const int*   item_cat    = (const int*)d_in[10];
    const int*   adj_row     = (const int*)d_in[11];
    const int*   adj_col     = (const int*)d_in[12];

    float* out = (float*)d_out;

    // workspace layout (all 16B aligned)
    float* A      = (float*)d_ws;                 // [NN*64]
    float* B      = A + (size_t)NN * 64;          // [NN*64]
    int2*  edges  = (int2*)(B + (size_t)NN * 64); // [NE]
    int*   offs   = (int*)(edges + NE);           // [NN] (also counts)
    int*   cursor = offs + NN;                    // [NN]
    int*   blksum = cursor + NN;                  // [512]

    // --- CSR build ---
    hipMemsetAsync(offs, 0, (size_t)NN * sizeof(int), stream);
    hist_k<<<5860, 256, 0, stream>>>(adj_row, offs);
    scan1_k<<<SCAN1_BLOCKS, 256, 0, stream>>>(offs, offs, blksum);
    scan2_k<<<1, 512, 0, stream>>>(blksum);
    addoff_k<<<1172, 256, 0, stream>>>(offs, blksum, cursor);
    scatter_k<<<5860, 256, 0, stream>>>(adj_row, adj_col, adj_val, cursor, edges);

    // --- layer-0 features into A (out contribution deferred to layer 1) ---
    user_init_k<<<12500, 256, 0, stream>>>(
        (const float4*)user_emb, (const float4*)gender_emb, (const float4*)age_emb,
        user_gender, user_age, (float4*)A);
    item_init_k<<<1563, 256, 0, stream>>>(
        item_bert, bert_w, item_emb, cat_emb, item_cat, A);

    // --- 3 propagation layers ---
    spmm_csr_k<<<18750, 256, 0, stream>>>(
        (const float4*)A, (float4*)B, (float4*)out, offs, cursor, edges, 1);
    spmm_csr_k<<<18750, 256, 0, stream>>>(
        (const float4*)B, (float4*)A, (float4*)out, offs, cursor, edges, 2);
    spmm_csr_k<<<18750, 256, 0, stream>>>(
        (const float4*)A, (float4*)B, (float4*)out, offs, cursor, edges, 3);
}